// Round 8
// baseline (147.676 us; speedup 1.0000x reference)
//
#include <hip/hip_runtime.h>

typedef __bf16 bfx8 __attribute__((ext_vector_type(8)));
typedef float fx4 __attribute__((ext_vector_type(4)));
typedef unsigned short us4 __attribute__((ext_vector_type(4)));
typedef unsigned short us8 __attribute__((ext_vector_type(8)));

#define NNODES 90
#define NPAD   96
#define HF     128
#define NGRAPH 512
#define EPG    1440                 // edges per graph
#define ETOT   (NGRAPH*EPG)
#define KTOT   34560                // 90*384
#define NKTOT  1080                 // KTOT/32
#define KSPLIT 45
#define KSTEPS (NKTOT/KSPLIT)       // 24

__device__ __forceinline__ unsigned short f2bf(float f){
  union { float f; unsigned u; } v; v.f = f;
  return (unsigned short)((v.u + 0x7FFFu + ((v.u>>16)&1u)) >> 16);
}
// H is stored with 16B-chunk XOR swizzle: elem (node,f) lives at
//   node*128 + ((f>>3) ^ (node&15))*8 + (f&7)
__device__ __forceinline__ int hsw(int node, int f){
  return node*HF + ((((f>>3) ^ (node&15)))<<3) + (f&7);
}

// ---- one kernel: pack lin1_W (blocks 0..1079), pack W1/W2/W3 (1080..1101)
__global__ __launch_bounds__(256) void pack_all_kern(
    const float* __restrict__ W1,
    const float* __restrict__ W2,
    const float* __restrict__ W3,
    const float* __restrict__ L1W,
    unsigned short* __restrict__ o1,
    unsigned short* __restrict__ o2,
    unsigned short* __restrict__ o3,
    unsigned short* __restrict__ l1p)
{
  __shared__ __align__(16) unsigned short tile[32*64];
  int b = blockIdx.x;
  int t = threadIdx.x;
  if (b < NKTOT) {                 // ---- lin1 pack: [34560][64] f32 -> frag layout
    int ks = b;
    fx4 a0 = *(const fx4*)&L1W[ks*2048 + t*8];
    fx4 a1 = *(const fx4*)&L1W[ks*2048 + t*8 + 4];
    us4 c0, c1;
#pragma unroll
    for (int j=0;j<4;j++){ c0[j] = f2bf(a0[j]); c1[j] = f2bf(a1[j]); }
    *(us4*)&tile[t*8]     = c0;
    *(us4*)&tile[t*8 + 4] = c1;
    __syncthreads();
    int lane = t & 63;
    int nt = t >> 6;
    int n  = nt*16 + (lane&15);
    int kq = (lane>>4)*8;
    us8 v;
#pragma unroll
    for (int j=0;j<8;j++) v[j] = tile[(kq+j)*64 + n];
    *(us8*)&l1p[((nt*NKTOT + ks)*64 + lane)*8] = v;
  } else {                         // ---- conv weight pack
    int bb = b - NKTOT;
    const float* W; unsigned short* out; int K, nK, tt;
    if (bb < 6)       { W = W1; out = o1; K = 90;  nK = 3; tt = bb*256 + t; }
    else if (bb < 14) { W = W2; out = o2; K = 128; nK = 4; tt = (bb-6)*256 + t; }
    else              { W = W3; out = o3; K = 128; nK = 4; tt = (bb-14)*256 + t; }
    int lane = tt & 63;
    int ks = (tt>>6) % nK;
    int nt = (tt>>6) / nK;
    int n  = nt*16 + (lane&15);
    int k0 = ks*32 + (lane>>4)*8;
    unsigned short v[8];
#pragma unroll
    for (int j=0;j<8;j++){ int k=k0+j; v[j] = (k<K)? f2bf(W[k*128+n]) : (unsigned short)0; }
    unsigned short* o = out + ((nt*nK+ks)*64 + lane)*8;
#pragma unroll
    for (int j=0;j<8;j++) o[j]=v[j];
  }
}

// ---- per-graph GCN, 512 threads (8 waves).
// LDS: Abf[90][96]bf16 @0 | H[90][128]bf16 (swizzled) @17280 | Tt[128][96]bf16 @40320
//      Af[90][96]f32 @17280 (phase0, overlaps H/Tt) | deg[96]f32 @64896
__global__ __launch_bounds__(512) void gcn_layers_kern(
    const float* __restrict__ x,
    const float* __restrict__ eattr,
    const int* __restrict__ ei,
    const unsigned short* __restrict__ w1p,
    const unsigned short* __restrict__ w2p,
    const unsigned short* __restrict__ w3p,
    const float* __restrict__ b1,
    const float* __restrict__ b2,
    const float* __restrict__ b3,
    unsigned short* __restrict__ xc)
{
  __shared__ __align__(16) char smem[65280];
  unsigned short* Abf = (unsigned short*)smem;
  unsigned short* H   = (unsigned short*)(smem + 17280);
  unsigned short* Tt  = (unsigned short*)(smem + 40320);
  float* Af  = (float*)(smem + 17280);
  float* deg = (float*)(smem + 64896);

  const int g = blockIdx.x;
  const int tid = threadIdx.x;
  const int lane = tid & 63, wave = tid >> 6;
  const int q = lane >> 4, r = lane & 15;
  const int eb = g*EPG;
  const int nb = g*NNODES;
  const long long* e64 = (const long long*)ei;

  // int-width detection (wave-uniform): i64 storage -> odd int32 words of the
  // first 64 entries are high words of small values == 0; i32 -> node ids != 0.
  bool i64f;
  {
    int v = ei[2*lane + 1];
    i64f = (__ballot(v != 0) == 0ull);
  }

  // ---- prefetch x (16 regs/thread): HBM latency overlaps all of phase 0
  float xr[16];
#pragma unroll
  for (int k = 0; k < 16; ++k) {
    int i = tid + k*512;
    xr[k] = (i < NNODES*90) ? x[nb*90 + i] : 0.f;
  }

  // ---- phase 0: edge prefetch into regs, zero Af, one atomic pass,
  //      deg = row-sum of raw A, separable normalization at conversion.
  const int e0 = tid, e1 = tid + 512, e2 = tid + 1024;
  const bool h2 = (e2 < EPG);
  int s0, d0, s1, d1, s2 = nb, d2 = nb;
  if (i64f) {
    s0 = (int)e64[eb+e0]; d0 = (int)e64[ETOT+eb+e0];
    s1 = (int)e64[eb+e1]; d1 = (int)e64[ETOT+eb+e1];
    if (h2) { s2 = (int)e64[eb+e2]; d2 = (int)e64[ETOT+eb+e2]; }
  } else {
    s0 = ei[eb+e0]; d0 = ei[ETOT+eb+e0];
    s1 = ei[eb+e1]; d1 = ei[ETOT+eb+e1];
    if (h2) { s2 = ei[eb+e2]; d2 = ei[ETOT+eb+e2]; }
  }
  float w0 = eattr[eb+e0];
  float w1 = eattr[eb+e1];
  float w2 = h2 ? eattr[eb+e2] : 0.f;

  for (int i = tid*4; i < NNODES*NPAD; i += 512*4) {
    fx4 zv = {0.f,0.f,0.f,0.f};
    *(fx4*)&Af[i] = zv;
  }
  __syncthreads();
  atomicAdd(&Af[(d0-nb)*NPAD + (s0-nb)], w0);
  atomicAdd(&Af[(d1-nb)*NPAD + (s1-nb)], w1);
  if (h2) atomicAdd(&Af[(d2-nb)*NPAD + (s2-nb)], w2);
  __syncthreads();
  // deg[row] = rsqrt(1 + sum_col Araw[row][*]); pad rows -> 1.0
  {
    int l16 = tid & 15;
    for (int row = tid >> 4; row < NPAD; row += 32) {
      float s = 0.f;
      if (row < NNODES) {
#pragma unroll
        for (int j = 0; j < 6; ++j) s += Af[row*NPAD + l16 + 16*j];
      }
      s += __shfl_xor(s, 1);
      s += __shfl_xor(s, 2);
      s += __shfl_xor(s, 4);
      s += __shfl_xor(s, 8);
      if (l16 == 0) deg[row] = (row < NNODES) ? rsqrtf(1.f + s) : 1.0f;
    }
  }
  __syncthreads();
  for (int i = tid; i < NNODES*NPAD; i += 512) {
    int row = i / NPAD, col = i - row*NPAD;
    float a = Af[i];
    if (col == row) a += 1.0f;                    // self-loop
    Abf[i] = f2bf(a * deg[row] * deg[col]);       // pad cols: Af=0 -> Abf=0
  }
  __syncthreads();                                // Af dead; H region free
  // write prefetched X into swizzled bf16 H (cols 90..95 zeroed: NaN-safe K-pad)
#pragma unroll
  for (int k = 0; k < 16; ++k) {
    int i = tid + k*512;
    if (i < NNODES*90) {
      int node = i/90, f = i - node*90;
      H[hsw(node, f)] = f2bf(xr[k]);
    }
  }
  for (int i = tid; i < NNODES*6; i += 512) {
    int node = i/6, f = 90 + (i - node*6);
    H[hsw(node, f)] = 0;
  }
  __syncthreads();

#pragma unroll
  for (int l = 0; l < 3; ++l) {
    const unsigned short* wpk = (l==0)? w1p : (l==1)? w2p : w3p;
    const float* bias         = (l==0)? b1 : (l==1)? b2 : b3;
    const int nK = (l==0)? 3 : 4;

    // hoisted B-frags for mm1 (nt = wave)
    bfx8 wf[4];
#pragma unroll
    for (int ks = 0; ks < 4; ++ks)
      if (ks < nK) wf[ks] = *(const bfx8*)(const void*)&wpk[((wave*nK + ks)*64 + lane)*8];

    // mm1: Tt = (H @ W)^T, wave owns nt = wave
    for (int mt = 0; mt < 6; ++mt) {
      int row = mt*16 + r; if (row > 89) row = 89;  // clamp; killed by A's zero cols
      fx4 acc = {0.f,0.f,0.f,0.f};
#pragma unroll
      for (int ks = 0; ks < 4; ++ks)
        if (ks < nK) {
          bfx8 af = *(const bfx8*)(const void*)&H[row*HF + (((4*ks + q) ^ (row&15))<<3)];
          acc = __builtin_amdgcn_mfma_f32_16x16x32_bf16(af, wf[ks], acc, 0,0,0);
        }
      us4 o;
#pragma unroll
      for (int i2=0;i2<4;i2++) o[i2] = f2bf(acc[i2]);
      *(us4*)&Tt[(wave*16 + r)*NPAD + mt*16 + q*4] = o;
    }
    __syncthreads();

    // agg: H' = relu(A@T + b) via S^T = T^T @ A^T, wave owns ft = wave.
    // xc written DIRECTLY from accumulator registers; H updated for next layer.
    {
      bfx8 tf[3];
#pragma unroll
      for (int ks = 0; ks < 3; ++ks)
        tf[ks] = *(const bfx8*)(const void*)&Tt[(wave*16 + r)*NPAD + ks*32 + q*8];
      float bv[4];
#pragma unroll
      for (int i2=0;i2<4;i2++) bv[i2] = bias[wave*16 + q*4 + i2];
      for (int nt = 0; nt < 6; ++nt) {
        int arow = nt*16 + r; if (arow > 89) arow = 89;
        fx4 acc = {0.f,0.f,0.f,0.f};
#pragma unroll
        for (int ks = 0; ks < 3; ++ks) {
          bfx8 bfr = *(const bfx8*)(const void*)&Abf[arow*NPAD + ks*32 + q*8];
          acc = __builtin_amdgcn_mfma_f32_16x16x32_bf16(tf[ks], bfr, acc, 0,0,0);
        }
        int m = nt*16 + r;                  // node
        if (m < NNODES) {
          us4 o;
#pragma unroll
          for (int i2=0;i2<4;i2++){
            float v = acc[i2] + bv[i2];
            o[i2] = f2bf(v > 0.f ? v : 0.f);
          }
          // global: feats wave*16+q*4 .. +3 of node m, layer slot l
          *(us4*)&xc[(nb + m)*384 + l*128 + wave*16 + q*4] = o;
          if (l < 2) {
            // LDS H for next layer: chunk = 2*wave + (q>>1), offset (q&1)*4
            *(us4*)&H[m*HF + (((2*wave + (q>>1)) ^ (m&15))<<3) + (q&1)*4] = o;
          }
        }
      }
    }
    if (l < 2) __syncthreads();   // H/Tt WAR for next layer; none needed after l=2
  }
}

// ---- head GEMM: [512,34560]@[34560,64], split-K=45, LDS-free, no atomics.
// grid = 8 mb x 45 kb; wave owns 16-row m-tile, all 4 n-tiles (A-frag reuse x4).
__global__ __launch_bounds__(256) void gemm2_kern(
    const unsigned short* __restrict__ z,   // xc viewed as [512][34560] bf16
    const unsigned short* __restrict__ wp,  // packed lin1_W bf16
    float* __restrict__ pbuf)               // [45][512][64] partials
{
  int mb = blockIdx.x % 8;
  int kb = blockIdx.x / 8;
  int tid = threadIdx.x;
  int lane = tid & 63, wave = tid >> 6;
  int q = lane >> 4, r = lane & 15;
  int m0 = mb*64;

  // A-frag: lane holds z[m0+wave*16+r][ksg*32 + q*8 .. +8]
  const unsigned short* zbase = &z[(m0 + wave*16 + r)*KTOT + (kb*KSTEPS)*32 + q*8];
  const unsigned short* wb = &wp[(kb*KSTEPS)*512 + lane*8];

  fx4 acc[4] = {{0,0,0,0},{0,0,0,0},{0,0,0,0},{0,0,0,0}};
#pragma unroll 4
  for (int it = 0; it < KSTEPS; ++it) {
    bfx8 af = *(const bfx8*)(const void*)&zbase[it*32];
#pragma unroll
    for (int nt = 0; nt < 4; ++nt) {
      bfx8 bf = *(const bfx8*)(const void*)&wb[(nt*NKTOT + it)*512];
      acc[nt] = __builtin_amdgcn_mfma_f32_16x16x32_bf16(af, bf, acc[nt], 0,0,0);
    }
  }
  float* pb = &pbuf[(kb*NGRAPH + m0 + wave*16)*64];
#pragma unroll
  for (int nt = 0; nt < 4; ++nt)
#pragma unroll
    for (int i2 = 0; i2 < 4; ++i2)
      pb[(q*4 + i2)*64 + nt*16 + r] = acc[nt][i2];
}

// ---- head: fold 45 split-K partials + bias + relu + lin2 + log_softmax; f32 out
__global__ __launch_bounds__(256) void head_kern(
    const float* __restrict__ pbuf,
    const float* __restrict__ l1b,
    const float* __restrict__ l2w,
    const float* __restrict__ l2b,
    float* __restrict__ out)
{
  int gph = blockIdx.x*4 + (threadIdx.x >> 6);
  int j = threadIdx.x & 63;
  float h = l1b[j];
  for (int kb = 0; kb < KSPLIT; ++kb)
    h += pbuf[(kb*NGRAPH + gph)*64 + j];
  h = h > 0.f ? h : 0.f;
  float p0 = h * l2w[2*j];
  float p1 = h * l2w[2*j+1];
  for (int off = 32; off; off >>= 1) {
    p0 += __shfl_down(p0, off);
    p1 += __shfl_down(p1, off);
  }
  if (j == 0) {
    float l0 = p0 + l2b[0];
    float l1 = p1 + l2b[1];
    float mx = fmaxf(l0, l1);
    float lse = mx + logf(expf(l0-mx) + expf(l1-mx));
    out[gph*2]   = l0 - lse;
    out[gph*2+1] = l1 - lse;
  }
}

extern "C" void kernel_launch(void* const* d_in, const int* in_sizes, int n_in,
                              void* d_out, int out_size, void* d_ws, size_t ws_size,
                              hipStream_t stream)
{
  const float* x   = (const float*)d_in[0];
  const float* ea  = (const float*)d_in[1];
  const float* W1  = (const float*)d_in[2];
  const float* b1  = (const float*)d_in[3];
  const float* W2  = (const float*)d_in[4];
  const float* b2  = (const float*)d_in[5];
  const float* W3  = (const float*)d_in[6];
  const float* b3  = (const float*)d_in[7];
  const float* L1W = (const float*)d_in[8];
  const float* L1b = (const float*)d_in[9];
  const float* L2W = (const float*)d_in[10];
  const float* L2b = (const float*)d_in[11];
  const int* ei    = (const int*)d_in[12];
  float* out       = (float*)d_out;

  char* ws = (char*)d_ws;
  unsigned short* xc  = (unsigned short*)(ws);             // 35,389,440 B
  unsigned short* l1p = (unsigned short*)(ws + 35389440);  //  4,423,680 B
  unsigned short* w1p = (unsigned short*)(ws + 39813120);  //     24,576 B
  unsigned short* w2p = (unsigned short*)(ws + 39837696);  //     32,768 B
  unsigned short* w3p = (unsigned short*)(ws + 39870464);  //     32,768 B
  float* pbuf         = (float*)(ws + 39903232);           //  5,898,240 B

  pack_all_kern<<<NKTOT + 22, 256, 0, stream>>>(W1, W2, W3, L1W,
                                                w1p, w2p, w3p, l1p);
  gcn_layers_kern<<<NGRAPH, 512, 0, stream>>>(x, ea, ei, w1p, w2p, w3p,
                                              b1, b2, b3, xc);
  gemm2_kern<<<8*KSPLIT, 256, 0, stream>>>(xc, l1p, pbuf);
  head_kern<<<NGRAPH/4, 256, 0, stream>>>(pbuf, L1b, L2W, L2b, out);
}

// Round 9
// 143.563 us; speedup vs baseline: 1.0287x; 1.0287x over previous
//
#include <hip/hip_runtime.h>

typedef __bf16 bfx8 __attribute__((ext_vector_type(8)));
typedef float fx4 __attribute__((ext_vector_type(4)));
typedef unsigned short us4 __attribute__((ext_vector_type(4)));
typedef unsigned short us8 __attribute__((ext_vector_type(8)));

#define NNODES 90
#define NPAD   96
#define HF     128
#define NGRAPH 512
#define EPG    1440                 // edges per graph
#define ETOT   (NGRAPH*EPG)
#define KTOT   34560                // 90*384
#define NKTOT  1080                 // KTOT/32
#define KSPLIT 90
#define KSTEPS (NKTOT/KSPLIT)       // 12

__device__ __forceinline__ unsigned short f2bf(float f){
  union { float f; unsigned u; } v; v.f = f;
  return (unsigned short)((v.u + 0x7FFFu + ((v.u>>16)&1u)) >> 16);
}
// H is stored with 16B-chunk XOR swizzle: elem (node,f) lives at
//   node*128 + ((f>>3) ^ (node&15))*8 + (f&7)
__device__ __forceinline__ int hsw(int node, int f){
  return node*HF + ((((f>>3) ^ (node&15)))<<3) + (f&7);
}

// ---- one kernel: pack lin1_W (blocks 0..1079), pack W1/W2/W3 (1080..1101)
__global__ __launch_bounds__(256) void pack_all_kern(
    const float* __restrict__ W1,
    const float* __restrict__ W2,
    const float* __restrict__ W3,
    const float* __restrict__ L1W,
    unsigned short* __restrict__ o1,
    unsigned short* __restrict__ o2,
    unsigned short* __restrict__ o3,
    unsigned short* __restrict__ l1p)
{
  __shared__ __align__(16) unsigned short tile[32*64];
  int b = blockIdx.x;
  int t = threadIdx.x;
  if (b < NKTOT) {                 // ---- lin1 pack: [34560][64] f32 -> frag layout
    int ks = b;
    fx4 a0 = *(const fx4*)&L1W[ks*2048 + t*8];
    fx4 a1 = *(const fx4*)&L1W[ks*2048 + t*8 + 4];
    us4 c0, c1;
#pragma unroll
    for (int j=0;j<4;j++){ c0[j] = f2bf(a0[j]); c1[j] = f2bf(a1[j]); }
    *(us4*)&tile[t*8]     = c0;
    *(us4*)&tile[t*8 + 4] = c1;
    __syncthreads();
    int lane = t & 63;
    int nt = t >> 6;
    int n  = nt*16 + (lane&15);
    int kq = (lane>>4)*8;
    us8 v;
#pragma unroll
    for (int j=0;j<8;j++) v[j] = tile[(kq+j)*64 + n];
    *(us8*)&l1p[((nt*NKTOT + ks)*64 + lane)*8] = v;
  } else {                         // ---- conv weight pack
    int bb = b - NKTOT;
    const float* W; unsigned short* out; int K, nK, tt;
    if (bb < 6)       { W = W1; out = o1; K = 90;  nK = 3; tt = bb*256 + t; }
    else if (bb < 14) { W = W2; out = o2; K = 128; nK = 4; tt = (bb-6)*256 + t; }
    else              { W = W3; out = o3; K = 128; nK = 4; tt = (bb-14)*256 + t; }
    int lane = tt & 63;
    int ks = (tt>>6) % nK;
    int nt = (tt>>6) / nK;
    int n  = nt*16 + (lane&15);
    int k0 = ks*32 + (lane>>4)*8;
    unsigned short v[8];
#pragma unroll
    for (int j=0;j<8;j++){ int k=k0+j; v[j] = (k<K)? f2bf(W[k*128+n]) : (unsigned short)0; }
    unsigned short* o = out + ((nt*nK+ks)*64 + lane)*8;
#pragma unroll
    for (int j=0;j<8;j++) o[j]=v[j];
  }
}

// ---- per-graph GCN, 512 threads (8 waves).
// LDS: Abf[90][96]bf16 @0 | H[90][128]bf16 (swizzled) @17280 | Tt[128][96]bf16 @40320
//      Af[90][96]f32 @17280 (phase0, overlaps H/Tt) | deg[96]f32 @64896
__global__ __launch_bounds__(512) void gcn_layers_kern(
    const float* __restrict__ x,
    const float* __restrict__ eattr,
    const int* __restrict__ ei,
    const unsigned short* __restrict__ w1p,
    const unsigned short* __restrict__ w2p,
    const unsigned short* __restrict__ w3p,
    const float* __restrict__ b1,
    const float* __restrict__ b2,
    const float* __restrict__ b3,
    unsigned short* __restrict__ xc)
{
  __shared__ __align__(16) char smem[65280];
  unsigned short* Abf = (unsigned short*)smem;
  unsigned short* H   = (unsigned short*)(smem + 17280);
  unsigned short* Tt  = (unsigned short*)(smem + 40320);
  float* Af  = (float*)(smem + 17280);
  float* deg = (float*)(smem + 64896);

  const int g = blockIdx.x;
  const int tid = threadIdx.x;
  const int lane = tid & 63, wave = tid >> 6;
  const int q = lane >> 4, r = lane & 15;
  const int eb = g*EPG;
  const int nb = g*NNODES;
  const long long* e64 = (const long long*)ei;

  // int-width detection (wave-uniform): i64 storage -> odd int32 words of the
  // first 64 entries are high words of small values == 0; i32 -> node ids != 0.
  bool i64f;
  {
    int v = ei[2*lane + 1];
    i64f = (__ballot(v != 0) == 0ull);
  }

  // ---- prefetch x (16 regs/thread): HBM latency overlaps all of phase 0
  float xr[16];
#pragma unroll
  for (int k = 0; k < 16; ++k) {
    int i = tid + k*512;
    xr[k] = (i < NNODES*90) ? x[nb*90 + i] : 0.f;
  }

  // ---- phase 0: edge prefetch into regs, zero Af, one atomic pass,
  //      deg = row-sum of raw A, separable normalization at conversion.
  const int e0 = tid, e1 = tid + 512, e2 = tid + 1024;
  const bool h2 = (e2 < EPG);
  int s0, d0, s1, d1, s2 = nb, d2 = nb;
  if (i64f) {
    s0 = (int)e64[eb+e0]; d0 = (int)e64[ETOT+eb+e0];
    s1 = (int)e64[eb+e1]; d1 = (int)e64[ETOT+eb+e1];
    if (h2) { s2 = (int)e64[eb+e2]; d2 = (int)e64[ETOT+eb+e2]; }
  } else {
    s0 = ei[eb+e0]; d0 = ei[ETOT+eb+e0];
    s1 = ei[eb+e1]; d1 = ei[ETOT+eb+e1];
    if (h2) { s2 = ei[eb+e2]; d2 = ei[ETOT+eb+e2]; }
  }
  float w0 = eattr[eb+e0];
  float w1 = eattr[eb+e1];
  float w2 = h2 ? eattr[eb+e2] : 0.f;

  for (int i = tid*4; i < NNODES*NPAD; i += 512*4) {
    fx4 zv = {0.f,0.f,0.f,0.f};
    *(fx4*)&Af[i] = zv;
  }
  __syncthreads();
  atomicAdd(&Af[(d0-nb)*NPAD + (s0-nb)], w0);
  atomicAdd(&Af[(d1-nb)*NPAD + (s1-nb)], w1);
  if (h2) atomicAdd(&Af[(d2-nb)*NPAD + (s2-nb)], w2);
  __syncthreads();
  // deg[row] = rsqrt(1 + sum_col Araw[row][*]); pad rows -> 1.0
  {
    int l16 = tid & 15;
    for (int row = tid >> 4; row < NPAD; row += 32) {
      float s = 0.f;
      if (row < NNODES) {
#pragma unroll
        for (int j = 0; j < 6; ++j) s += Af[row*NPAD + l16 + 16*j];
      }
      s += __shfl_xor(s, 1);
      s += __shfl_xor(s, 2);
      s += __shfl_xor(s, 4);
      s += __shfl_xor(s, 8);
      if (l16 == 0) deg[row] = (row < NNODES) ? rsqrtf(1.f + s) : 1.0f;
    }
  }
  __syncthreads();
  for (int i = tid; i < NNODES*NPAD; i += 512) {
    int row = i / NPAD, col = i - row*NPAD;
    float a = Af[i];
    if (col == row) a += 1.0f;                    // self-loop
    Abf[i] = f2bf(a * deg[row] * deg[col]);       // pad cols: Af=0 -> Abf=0
  }
  __syncthreads();                                // Af dead; H region free
  // write prefetched X into swizzled bf16 H (cols 90..95 zeroed: NaN-safe K-pad)
#pragma unroll
  for (int k = 0; k < 16; ++k) {
    int i = tid + k*512;
    if (i < NNODES*90) {
      int node = i/90, f = i - node*90;
      H[hsw(node, f)] = f2bf(xr[k]);
    }
  }
  for (int i = tid; i < NNODES*6; i += 512) {
    int node = i/6, f = 90 + (i - node*6);
    H[hsw(node, f)] = 0;
  }
  __syncthreads();

#pragma unroll
  for (int l = 0; l < 3; ++l) {
    const unsigned short* wpk = (l==0)? w1p : (l==1)? w2p : w3p;
    const float* bias         = (l==0)? b1 : (l==1)? b2 : b3;
    const int nK = (l==0)? 3 : 4;

    // hoisted B-frags for mm1 (nt = wave)
    bfx8 wf[4];
#pragma unroll
    for (int ks = 0; ks < 4; ++ks)
      if (ks < nK) wf[ks] = *(const bfx8*)(const void*)&wpk[((wave*nK + ks)*64 + lane)*8];

    // mm1: Tt = (H @ W)^T, wave owns nt = wave
    for (int mt = 0; mt < 6; ++mt) {
      int row = mt*16 + r; if (row > 89) row = 89;  // clamp; killed by A's zero cols
      fx4 acc = {0.f,0.f,0.f,0.f};
#pragma unroll
      for (int ks = 0; ks < 4; ++ks)
        if (ks < nK) {
          bfx8 af = *(const bfx8*)(const void*)&H[row*HF + (((4*ks + q) ^ (row&15))<<3)];
          acc = __builtin_amdgcn_mfma_f32_16x16x32_bf16(af, wf[ks], acc, 0,0,0);
        }
      us4 o;
#pragma unroll
      for (int i2=0;i2<4;i2++) o[i2] = f2bf(acc[i2]);
      *(us4*)&Tt[(wave*16 + r)*NPAD + mt*16 + q*4] = o;
    }
    __syncthreads();

    // agg: H' = relu(A@T + b) via S^T = T^T @ A^T, wave owns ft = wave.
    // xc written DIRECTLY from accumulator registers; H updated for next layer.
    {
      bfx8 tf[3];
#pragma unroll
      for (int ks = 0; ks < 3; ++ks)
        tf[ks] = *(const bfx8*)(const void*)&Tt[(wave*16 + r)*NPAD + ks*32 + q*8];
      float bv[4];
#pragma unroll
      for (int i2=0;i2<4;i2++) bv[i2] = bias[wave*16 + q*4 + i2];
      for (int nt = 0; nt < 6; ++nt) {
        int arow = nt*16 + r; if (arow > 89) arow = 89;
        fx4 acc = {0.f,0.f,0.f,0.f};
#pragma unroll
        for (int ks = 0; ks < 3; ++ks) {
          bfx8 bfr = *(const bfx8*)(const void*)&Abf[arow*NPAD + ks*32 + q*8];
          acc = __builtin_amdgcn_mfma_f32_16x16x32_bf16(tf[ks], bfr, acc, 0,0,0);
        }
        int m = nt*16 + r;                  // node
        if (m < NNODES) {
          us4 o;
#pragma unroll
          for (int i2=0;i2<4;i2++){
            float v = acc[i2] + bv[i2];
            o[i2] = f2bf(v > 0.f ? v : 0.f);
          }
          // global: feats wave*16+q*4 .. +3 of node m, layer slot l
          *(us4*)&xc[(nb + m)*384 + l*128 + wave*16 + q*4] = o;
          if (l < 2) {
            // LDS H for next layer: chunk = 2*wave + (q>>1), offset (q&1)*4
            *(us4*)&H[m*HF + (((2*wave + (q>>1)) ^ (m&15))<<3) + (q&1)*4] = o;
          }
        }
      }
    }
    if (l < 2) __syncthreads();   // H/Tt WAR for next layer; none needed after l=2
  }
}

// ---- head GEMM: [512,34560]@[34560,64], split-K=90, wp LDS-staged (no 4x
//      wave redundancy), z direct-global A-frags, no atomics.
// grid = 8 mb x 90 kb; wave owns 16-row m-tile, all 4 n-tiles.
__global__ __launch_bounds__(256) void gemm2_kern(
    const unsigned short* __restrict__ z,   // xc viewed as [512][34560] bf16
    const unsigned short* __restrict__ wp,  // packed lin1_W bf16
    float* __restrict__ pbuf)               // [90][512][64] partials
{
  __shared__ __align__(16) unsigned short wlds[4*6*512];  // 24 KB: [nt][it6][512]
  int mb = blockIdx.x & 7;
  int kb = blockIdx.x >> 3;
  int tid = threadIdx.x;
  int lane = tid & 63, wave = tid >> 6;
  int q = lane >> 4, r = lane & 15;
  int m0 = mb*64;

  // A-frag: lane holds z[m0+wave*16+r][ksg*32 + q*8 .. +8]
  const unsigned short* zbase = &z[(m0 + wave*16 + r)*KTOT + (kb*KSTEPS)*32 + q*8];

  fx4 acc[4] = {{0,0,0,0},{0,0,0,0},{0,0,0,0},{0,0,0,0}};
#pragma unroll
  for (int c = 0; c < 2; ++c) {            // two 6-step chunks
    // stage wp chunk: 1536 us8s, 6 per thread, coalesced
#pragma unroll
    for (int k = 0; k < 6; ++k) {
      int u = tid + k*256;                 // us8 index
      int nt = u / 384, i = u - nt*384;
      *(us8*)&wlds[u*8] =
        *(const us8*)&wp[(nt*NKTOT + kb*KSTEPS + c*6)*512 + i*8];
    }
    __syncthreads();
#pragma unroll
    for (int ii = 0; ii < 6; ++ii) {
      bfx8 af = *(const bfx8*)(const void*)&zbase[(c*6 + ii)*32];
#pragma unroll
      for (int nt = 0; nt < 4; ++nt) {
        bfx8 bf = *(const bfx8*)(const void*)&wlds[(nt*6 + ii)*512 + lane*8];
        acc[nt] = __builtin_amdgcn_mfma_f32_16x16x32_bf16(af, bf, acc[nt], 0,0,0);
      }
    }
    __syncthreads();                       // WAR before next stage
  }
  float* pb = &pbuf[(kb*NGRAPH + m0 + wave*16)*64];
#pragma unroll
  for (int nt = 0; nt < 4; ++nt)
#pragma unroll
    for (int i2 = 0; i2 < 4; ++i2)
      pb[(q*4 + i2)*64 + nt*16 + r] = acc[nt][i2];
}

// ---- head: fold 90 split-K partials + bias + relu + lin2 + log_softmax; f32 out
__global__ __launch_bounds__(256) void head_kern(
    const float* __restrict__ pbuf,
    const float* __restrict__ l1b,
    const float* __restrict__ l2w,
    const float* __restrict__ l2b,
    float* __restrict__ out)
{
  int gph = blockIdx.x*4 + (threadIdx.x >> 6);
  int j = threadIdx.x & 63;
  float h = l1b[j];
  for (int kb = 0; kb < KSPLIT; ++kb)
    h += pbuf[(kb*NGRAPH + gph)*64 + j];
  h = h > 0.f ? h : 0.f;
  float p0 = h * l2w[2*j];
  float p1 = h * l2w[2*j+1];
  for (int off = 32; off; off >>= 1) {
    p0 += __shfl_down(p0, off);
    p1 += __shfl_down(p1, off);
  }
  if (j == 0) {
    float l0 = p0 + l2b[0];
    float l1 = p1 + l2b[1];
    float mx = fmaxf(l0, l1);
    float lse = mx + logf(expf(l0-mx) + expf(l1-mx));
    out[gph*2]   = l0 - lse;
    out[gph*2+1] = l1 - lse;
  }
}

extern "C" void kernel_launch(void* const* d_in, const int* in_sizes, int n_in,
                              void* d_out, int out_size, void* d_ws, size_t ws_size,
                              hipStream_t stream)
{
  const float* x   = (const float*)d_in[0];
  const float* ea  = (const float*)d_in[1];
  const float* W1  = (const float*)d_in[2];
  const float* b1  = (const float*)d_in[3];
  const float* W2  = (const float*)d_in[4];
  const float* b2  = (const float*)d_in[5];
  const float* W3  = (const float*)d_in[6];
  const float* b3  = (const float*)d_in[7];
  const float* L1W = (const float*)d_in[8];
  const float* L1b = (const float*)d_in[9];
  const float* L2W = (const float*)d_in[10];
  const float* L2b = (const float*)d_in[11];
  const int* ei    = (const int*)d_in[12];
  float* out       = (float*)d_out;

  char* ws = (char*)d_ws;
  unsigned short* xc  = (unsigned short*)(ws);             // 35,389,440 B
  unsigned short* l1p = (unsigned short*)(ws + 35389440);  //  4,423,680 B
  unsigned short* w1p = (unsigned short*)(ws + 39813120);  //     24,576 B
  unsigned short* w2p = (unsigned short*)(ws + 39837696);  //     32,768 B
  unsigned short* w3p = (unsigned short*)(ws + 39870464);  //     32,768 B
  float* pbuf         = (float*)(ws + 39903232);           // 11,796,480 B

  pack_all_kern<<<NKTOT + 22, 256, 0, stream>>>(W1, W2, W3, L1W,
                                                w1p, w2p, w3p, l1p);
  gcn_layers_kern<<<NGRAPH, 512, 0, stream>>>(x, ea, ei, w1p, w2p, w3p,
                                              b1, b2, b3, xc);
  gemm2_kern<<<8*KSPLIT, 256, 0, stream>>>(xc, l1p, pbuf);
  head_kern<<<NGRAPH/4, 256, 0, stream>>>(pbuf, L1b, L2W, L2b, out);
}